// Round 1
// baseline (7084.666 us; speedup 1.0000x reference)
//
#include <hip/hip_runtime.h>
#include <hip/hip_bf16.h>
#include <cstdint>
#include <cstddef>

typedef __attribute__((ext_vector_type(4))) float floatx4;
typedef __attribute__((ext_vector_type(8))) short shortx8;

#define T_SEQ 512
#define NIN   512
#define BATCH 256
#define HID   256
#define G3    768
#define NC    101

static __device__ __forceinline__ unsigned short f2bf(float f){
  unsigned int u = __float_as_uint(f);
  u += 0x7FFFu + ((u >> 16) & 1u);
  return (unsigned short)(u >> 16);
}

// ---------------- Phase A: xg[b*Tc+tt][n] = x[b, t0+tt, :] . Wih[n, :] + bih[n]
// bf16 MFMA 16x16x32, BM=BN=128, BK=64, fp32 accumulate.
#define BM 128
#define BN 128
#define BK 64
#define LDK 72   // padded leading dim (bf16 elems): 144B row stride -> 2-way bank alias only

__global__ __launch_bounds__(256) void gemm_xg(
    const float* __restrict__ x, const float* __restrict__ Wih,
    const float* __restrict__ bih, float* __restrict__ xg,
    int t0, int tcLog2)
{
  __shared__ unsigned short As[BM*LDK];
  __shared__ unsigned short Bs[BN*LDK];
  const int tid  = threadIdx.x;
  const int bm   = blockIdx.x;
  const int bn   = blockIdx.y;
  const int w    = tid >> 6;
  const int l    = tid & 63;
  const int lm   = l & 15;
  const int quad = l >> 4;

  const int srow = tid >> 4;        // 0..15
  const int scol = (tid & 15) * 4;  // 0..60
  const int tcMask = (1 << tcLog2) - 1;

  floatx4 acc[2][8];
  #pragma unroll
  for (int mt = 0; mt < 2; ++mt)
    #pragma unroll
    for (int nt = 0; nt < 8; ++nt)
      acc[mt][nt] = (floatx4){0.f, 0.f, 0.f, 0.f};

  for (int kt = 0; kt < NIN / BK; ++kt){
    const int k0 = kt * BK;
    __syncthreads();
    #pragma unroll
    for (int p = 0; p < 8; ++p){
      const int r  = p * 16 + srow;
      // A tile (x rows, converted fp32 -> bf16)
      const int gm = bm * BM + r;
      const int b  = gm >> tcLog2;
      const int tt = gm & tcMask;
      const float4 xa = *(const float4*)(x + (size_t)(b * T_SEQ + t0 + tt) * NIN + k0 + scol);
      union { unsigned short u[4]; uint2 v; } pa;
      pa.u[0] = f2bf(xa.x); pa.u[1] = f2bf(xa.y); pa.u[2] = f2bf(xa.z); pa.u[3] = f2bf(xa.w);
      *(uint2*)&As[r * LDK + scol] = pa.v;
      // B tile (Wih rows)
      const int gn = bn * BN + r;
      const float4 wb = *(const float4*)(Wih + (size_t)gn * NIN + k0 + scol);
      union { unsigned short u[4]; uint2 v; } pb;
      pb.u[0] = f2bf(wb.x); pb.u[1] = f2bf(wb.y); pb.u[2] = f2bf(wb.z); pb.u[3] = f2bf(wb.w);
      *(uint2*)&Bs[r * LDK + scol] = pb.v;
    }
    __syncthreads();
    #pragma unroll
    for (int ks = 0; ks < 2; ++ks){
      const int kk = ks * 32 + quad * 8;
      shortx8 af[2], bf[8];
      #pragma unroll
      for (int mt = 0; mt < 2; ++mt)
        af[mt] = *(const shortx8*)&As[(w * 32 + mt * 16 + lm) * LDK + kk];
      #pragma unroll
      for (int nt = 0; nt < 8; ++nt)
        bf[nt] = *(const shortx8*)&Bs[(nt * 16 + lm) * LDK + kk];
      #pragma unroll
      for (int mt = 0; mt < 2; ++mt)
        #pragma unroll
        for (int nt = 0; nt < 8; ++nt)
          acc[mt][nt] = __builtin_amdgcn_mfma_f32_16x16x32_bf16(af[mt], bf[nt], acc[mt][nt], 0, 0, 0);
    }
  }

  // Epilogue: C/D layout col=lane&15, row=quad*4+reg  (m89/m91-verified)
  #pragma unroll
  for (int mt = 0; mt < 2; ++mt){
    #pragma unroll
    for (int nt = 0; nt < 8; ++nt){
      #pragma unroll
      for (int i = 0; i < 4; ++i){
        const int ml = w * 32 + mt * 16 + quad * 4 + i;
        const int nl = nt * 16 + lm;
        const int gm = bm * BM + ml;
        const int gn = bn * BN + nl;
        xg[(size_t)gm * G3 + gn] = acc[mt][nt][i] + bih[gn];
      }
    }
  }
}

// ---------------- Phase B: sequential GRU steps. One 768-thread WG per batch row.
// Thread j holds W_hh row j in 256 VGPRs; h lives in LDS (broadcast reads).
__global__ __launch_bounds__(768, 1) void gru_steps(
    const float* __restrict__ xg, const float* __restrict__ Whh,
    const float* __restrict__ bhh, float* __restrict__ hstate, int Tc)
{
  __shared__ float hs[HID];
  __shared__ float rbuf[HID];
  __shared__ float zbuf[HID];
  const int b = blockIdx.x;
  const int j = threadIdx.x;

  float4 wr[64];
  const float4* W4 = (const float4*)(Whh + (size_t)j * HID);
  #pragma unroll
  for (int k = 0; k < 64; ++k) wr[k] = W4[k];
  const float bias = bhh[j];

  if (j < HID) hs[j] = hstate[b * HID + j];
  __syncthreads();

  const float* xgrow = xg + (size_t)b * Tc * G3 + j;
  for (int t = 0; t < Tc; ++t){
    const float xv = xgrow[(size_t)t * G3];
    // dot(Whh[j,:], h) with 4 independent accumulator chains
    float4 a4 = {0.f, 0.f, 0.f, 0.f};
    const float4* h4 = (const float4*)hs;
    #pragma unroll
    for (int k = 0; k < 64; ++k){
      const float4 hv = h4[k];
      a4.x = fmaf(wr[k].x, hv.x, a4.x);
      a4.y = fmaf(wr[k].y, hv.y, a4.y);
      a4.z = fmaf(wr[k].z, hv.z, a4.z);
      a4.w = fmaf(wr[k].w, hv.w, a4.w);
    }
    const float dot = (a4.x + a4.y) + (a4.z + a4.w) + bias;

    const float sig = 1.f / (1.f + __expf(-(xv + dot)));
    if (j < 256)      rbuf[j]       = sig;
    else if (j < 512) zbuf[j - 256] = sig;
    __syncthreads();
    if (j >= 512){
      const int jj = j - 512;
      const float n = tanhf(xv + rbuf[jj] * dot);   // dot here = hn (incl. b_hh)
      const float z = zbuf[jj];
      hs[jj] = fmaf(z, hs[jj] - n, n);              // (1-z)*n + z*h
    }
    __syncthreads();
  }

  if (j < HID) hstate[b * HID + j] = hs[j];
}

// ---------------- FC: out[b][c] = h[b,:] . fc_w[c,:] + fc_b[c]
__global__ __launch_bounds__(128) void fc_kernel(
    const float* __restrict__ hstate, const float* __restrict__ fw,
    const float* __restrict__ fb, float* __restrict__ out)
{
  __shared__ float hs[HID];
  const int b = blockIdx.x;
  const int t = threadIdx.x;
  hs[t]       = hstate[b * HID + t];
  hs[t + 128] = hstate[b * HID + t + 128];
  __syncthreads();
  if (t < NC){
    float acc = fb[t];
    const float4* w4 = (const float4*)(fw + (size_t)t * HID);
    const float4* h4 = (const float4*)hs;
    #pragma unroll
    for (int k = 0; k < 64; ++k){
      const float4 wv = w4[k];
      const float4 hv = h4[k];
      acc += wv.x * hv.x + wv.y * hv.y + wv.z * hv.z + wv.w * hv.w;
    }
    out[b * NC + t] = acc;
  }
}

extern "C" void kernel_launch(void* const* d_in, const int* in_sizes, int n_in,
                              void* d_out, int out_size, void* d_ws, size_t ws_size,
                              hipStream_t stream)
{
  const float* x   = (const float*)d_in[0];
  const float* Wih = (const float*)d_in[1];
  const float* Whh = (const float*)d_in[2];
  const float* bih = (const float*)d_in[3];
  const float* bhh = (const float*)d_in[4];
  const float* fcw = (const float*)d_in[5];
  const float* fcb = (const float*)d_in[6];
  float* out = (float*)d_out;

  float* hst = (float*)d_ws;
  const size_t hBytes = (size_t)BATCH * HID * sizeof(float);
  float* xg  = (float*)((char*)d_ws + hBytes);

  // Largest power-of-2 T-chunk whose xg buffer fits the workspace.
  const size_t perT = (size_t)BATCH * G3 * sizeof(float);
  const size_t avail = (ws_size > hBytes) ? (ws_size - hBytes) : 0;
  int tcLog2 = 9;
  while (tcLog2 > 0 && perT * ((size_t)1 << tcLog2) > avail) --tcLog2;
  const int Tc = 1 << tcLog2;

  hipMemsetAsync(hst, 0, hBytes, stream);
  for (int t0 = 0; t0 < T_SEQ; t0 += Tc){
    dim3 grid(2 * Tc, 6);
    gemm_xg<<<grid, 256, 0, stream>>>(x, Wih, bih, xg, t0, tcLog2);
    gru_steps<<<BATCH, 768, 0, stream>>>(xg, Whh, bhh, hst, Tc);
  }
  fc_kernel<<<BATCH, 128, 0, stream>>>(hst, fcw, fcb, out);
}

// Round 3
// 2217.467 us; speedup vs baseline: 3.1949x; 3.1949x over previous
//
#include <hip/hip_runtime.h>
#include <hip/hip_bf16.h>
#include <cstdint>
#include <cstddef>

typedef __attribute__((ext_vector_type(4))) float floatx4;
typedef __attribute__((ext_vector_type(8))) short shortx8;
typedef __attribute__((ext_vector_type(2))) __fp16 f16x2;

#define T_SEQ 512
#define NIN   512
#define BATCH 256
#define HID   256
#define G3    768
#define NC    101

static __device__ __forceinline__ unsigned short f2bf(float f){
  unsigned int u = __float_as_uint(f);
  u += 0x7FFFu + ((u >> 16) & 1u);
  return (unsigned short)(u >> 16);
}

static __device__ __forceinline__ float dot2acc(f16x2 w, f16x2 h, float acc){
#if __has_builtin(__builtin_amdgcn_fdot2)
  return __builtin_amdgcn_fdot2(w, h, acc, false);
#else
  return acc + (float)w[0]*(float)h[0] + (float)w[1]*(float)h[1];
#endif
}

// ---------------- Phase A: xg[b*Tc+tt][n] = x[b, t0+tt, :] . Wih[n, :] + bih[n]
// bf16 MFMA 16x16x32, BM=BN=128, BK=64, fp32 accumulate.
#define BM 128
#define BN 128
#define BK 64
#define LDK 72   // padded leading dim (bf16 elems)

__global__ __launch_bounds__(256) void gemm_xg(
    const float* __restrict__ x, const float* __restrict__ Wih,
    const float* __restrict__ bih, float* __restrict__ xg,
    int t0, int tcLog2)
{
  __shared__ unsigned short As[BM*LDK];
  __shared__ unsigned short Bs[BN*LDK];
  const int tid  = threadIdx.x;
  const int bm   = blockIdx.x;
  const int bn   = blockIdx.y;
  const int w    = tid >> 6;
  const int l    = tid & 63;
  const int lm   = l & 15;
  const int quad = l >> 4;

  const int srow = tid >> 4;        // 0..15
  const int scol = (tid & 15) * 4;  // 0..60
  const int tcMask = (1 << tcLog2) - 1;

  floatx4 acc[2][8];
  #pragma unroll
  for (int mt = 0; mt < 2; ++mt)
    #pragma unroll
    for (int nt = 0; nt < 8; ++nt)
      acc[mt][nt] = (floatx4){0.f, 0.f, 0.f, 0.f};

  for (int kt = 0; kt < NIN / BK; ++kt){
    const int k0 = kt * BK;
    __syncthreads();
    #pragma unroll
    for (int p = 0; p < 8; ++p){
      const int r  = p * 16 + srow;
      const int gm = bm * BM + r;
      const int b  = gm >> tcLog2;
      const int tt = gm & tcMask;
      const float4 xa = *(const float4*)(x + (size_t)(b * T_SEQ + t0 + tt) * NIN + k0 + scol);
      union { unsigned short u[4]; uint2 v; } pa;
      pa.u[0] = f2bf(xa.x); pa.u[1] = f2bf(xa.y); pa.u[2] = f2bf(xa.z); pa.u[3] = f2bf(xa.w);
      *(uint2*)&As[r * LDK + scol] = pa.v;
      const int gn = bn * BN + r;
      const float4 wb = *(const float4*)(Wih + (size_t)gn * NIN + k0 + scol);
      union { unsigned short u[4]; uint2 v; } pb;
      pb.u[0] = f2bf(wb.x); pb.u[1] = f2bf(wb.y); pb.u[2] = f2bf(wb.z); pb.u[3] = f2bf(wb.w);
      *(uint2*)&Bs[r * LDK + scol] = pb.v;
    }
    __syncthreads();
    #pragma unroll
    for (int ks = 0; ks < 2; ++ks){
      const int kk = ks * 32 + quad * 8;
      shortx8 af[2], bfr[8];
      #pragma unroll
      for (int mt = 0; mt < 2; ++mt)
        af[mt] = *(const shortx8*)&As[(w * 32 + mt * 16 + lm) * LDK + kk];
      #pragma unroll
      for (int nt = 0; nt < 8; ++nt)
        bfr[nt] = *(const shortx8*)&Bs[(nt * 16 + lm) * LDK + kk];
      #pragma unroll
      for (int mt = 0; mt < 2; ++mt)
        #pragma unroll
        for (int nt = 0; nt < 8; ++nt)
          acc[mt][nt] = __builtin_amdgcn_mfma_f32_16x16x32_bf16(af[mt], bfr[nt], acc[mt][nt], 0, 0, 0);
    }
  }

  #pragma unroll
  for (int mt = 0; mt < 2; ++mt){
    #pragma unroll
    for (int nt = 0; nt < 8; ++nt){
      #pragma unroll
      for (int i = 0; i < 4; ++i){
        const int ml = w * 32 + mt * 16 + quad * 4 + i;
        const int nl = nt * 16 + lm;
        const int gm = bm * BM + ml;
        const int gn = bn * BN + nl;
        xg[(size_t)gm * G3 + gn] = acc[mt][nt][i] + bih[gn];
      }
    }
  }
}

// ---------------- Phase B: sequential GRU. One 256-thread WG per batch element.
// Thread j owns Whh rows {j, j+256, j+512} as f16 pairs in 384 VGPRs and
// computes ALL THREE gates for hidden index j (no r/z exchange needed).
// h: fp32 master in a register; f16-packed mirror in LDS (512 B) for the
// broadcast dot reads. 4 waves = 1 wave/SIMD -> 512-VGPR budget.
__global__ __launch_bounds__(256, 1) void gru_steps(
    const float* __restrict__ xg, const float* __restrict__ Whh,
    const float* __restrict__ bhh, float* __restrict__ hstate, int Tc)
{
  __shared__ alignas(16) unsigned short hph[HID];  // packed f16 h
  const int b = blockIdx.x;
  const int j = threadIdx.x;

  // Load + convert the 3 weight rows into registers (f16 pairs).
  f16x2 wrr[128], wrz[128], wrn[128];
  {
    const float4* r4 = (const float4*)(Whh + (size_t)j * HID);
    const float4* z4 = (const float4*)(Whh + (size_t)(j + 256) * HID);
    const float4* n4 = (const float4*)(Whh + (size_t)(j + 512) * HID);
    #pragma unroll
    for (int k = 0; k < 64; ++k){
      float4 v = r4[k];
      wrr[2*k]   = __builtin_amdgcn_cvt_pkrtz(v.x, v.y);
      wrr[2*k+1] = __builtin_amdgcn_cvt_pkrtz(v.z, v.w);
    }
    #pragma unroll
    for (int k = 0; k < 64; ++k){
      float4 v = z4[k];
      wrz[2*k]   = __builtin_amdgcn_cvt_pkrtz(v.x, v.y);
      wrz[2*k+1] = __builtin_amdgcn_cvt_pkrtz(v.z, v.w);
    }
    #pragma unroll
    for (int k = 0; k < 64; ++k){
      float4 v = n4[k];
      wrn[2*k]   = __builtin_amdgcn_cvt_pkrtz(v.x, v.y);
      wrn[2*k+1] = __builtin_amdgcn_cvt_pkrtz(v.z, v.w);
    }
  }
  const float br = bhh[j];
  const float bz = bhh[j + 256];
  const float bn = bhh[j + 512];

  float hj = hstate[b * HID + j];
  {
    union { __fp16 f; unsigned short u; } cv;
    cv.f = (__fp16)hj;
    hph[j] = cv.u;
  }
  __syncthreads();

  const float* xgrow = xg + (size_t)b * Tc * G3 + j;

  #pragma unroll 1
  for (int t = 0; t < Tc; ++t){
    const float xr = xgrow[(size_t)t * G3];
    const float xz = xgrow[(size_t)t * G3 + 256];
    const float xn = xgrow[(size_t)t * G3 + 512];

    // Three dots of length 256, reading broadcast f16 pairs from LDS.
    float ar0 = 0.f, ar1 = 0.f, az0 = 0.f, az1 = 0.f, an0 = 0.f, an1 = 0.f;
    const uint4* hp4 = (const uint4*)hph;   // 32 x (4 pairs)
    #pragma unroll
    for (int i = 0; i < 32; ++i){
      const uint4 hv = hp4[i];
      union { unsigned int u; f16x2 h; } c0, c1, c2, c3;
      c0.u = hv.x; c1.u = hv.y; c2.u = hv.z; c3.u = hv.w;
      const int p = 4 * i;
      ar0 = dot2acc(wrr[p    ], c0.h, ar0);
      az0 = dot2acc(wrz[p    ], c0.h, az0);
      an0 = dot2acc(wrn[p    ], c0.h, an0);
      ar1 = dot2acc(wrr[p + 1], c1.h, ar1);
      az1 = dot2acc(wrz[p + 1], c1.h, az1);
      an1 = dot2acc(wrn[p + 1], c1.h, an1);
      ar0 = dot2acc(wrr[p + 2], c2.h, ar0);
      az0 = dot2acc(wrz[p + 2], c2.h, az0);
      an0 = dot2acc(wrn[p + 2], c2.h, an0);
      ar1 = dot2acc(wrr[p + 3], c3.h, ar1);
      az1 = dot2acc(wrz[p + 3], c3.h, az1);
      an1 = dot2acc(wrn[p + 3], c3.h, an1);
    }
    const float hr = ar0 + ar1 + br;
    const float hz = az0 + az1 + bz;
    const float hn = an0 + an1 + bn;

    const float r = 1.f / (1.f + __expf(-(xr + hr)));
    const float z = 1.f / (1.f + __expf(-(xz + hz)));
    const float a = xn + r * hn;
    // tanh via exp, sign-symmetric
    const float ex = __expf(-2.f * fabsf(a));
    float n = (1.f - ex) / (1.f + ex);
    n = copysignf(n, a);
    const float hnew = fmaf(z, hj - n, n);   // (1-z)*n + z*h

    __syncthreads();   // all dot reads of old h done
    hj = hnew;
    union { __fp16 f; unsigned short u; } cv;
    cv.f = (__fp16)hj;
    hph[j] = cv.u;
    __syncthreads();   // new h visible
  }

  hstate[b * HID + j] = hj;
}

// ---------------- FC: out[b][c] = h[b,:] . fc_w[c,:] + fc_b[c]
__global__ __launch_bounds__(128) void fc_kernel(
    const float* __restrict__ hstate, const float* __restrict__ fw,
    const float* __restrict__ fb, float* __restrict__ out)
{
  __shared__ float hs[HID];
  const int b = blockIdx.x;
  const int t = threadIdx.x;
  hs[t]       = hstate[b * HID + t];
  hs[t + 128] = hstate[b * HID + t + 128];
  __syncthreads();
  if (t < NC){
    float acc = fb[t];
    const float4* w4 = (const float4*)(fw + (size_t)t * HID);
    const float4* h4 = (const float4*)hs;
    #pragma unroll
    for (int k = 0; k < 64; ++k){
      const float4 wv = w4[k];
      const float4 hv = h4[k];
      acc += wv.x * hv.x + wv.y * hv.y + wv.z * hv.z + wv.w * hv.w;
    }
    out[b * NC + t] = acc;
  }
}

extern "C" void kernel_launch(void* const* d_in, const int* in_sizes, int n_in,
                              void* d_out, int out_size, void* d_ws, size_t ws_size,
                              hipStream_t stream)
{
  const float* x   = (const float*)d_in[0];
  const float* Wih = (const float*)d_in[1];
  const float* Whh = (const float*)d_in[2];
  const float* bih = (const float*)d_in[3];
  const float* bhh = (const float*)d_in[4];
  const float* fcw = (const float*)d_in[5];
  const float* fcb = (const float*)d_in[6];
  float* out = (float*)d_out;

  float* hst = (float*)d_ws;
  const size_t hBytes = (size_t)BATCH * HID * sizeof(float);
  float* xg  = (float*)((char*)d_ws + hBytes);

  const size_t perT = (size_t)BATCH * G3 * sizeof(float);
  const size_t avail = (ws_size > hBytes) ? (ws_size - hBytes) : 0;
  int tcLog2 = 9;
  while (tcLog2 > 0 && perT * ((size_t)1 << tcLog2) > avail) --tcLog2;
  const int Tc = 1 << tcLog2;

  (void)hipMemsetAsync(hst, 0, hBytes, stream);
  for (int t0 = 0; t0 < T_SEQ; t0 += Tc){
    dim3 grid(2 * Tc, 6);
    gemm_xg<<<grid, 256, 0, stream>>>(x, Wih, bih, xg, t0, tcLog2);
    gru_steps<<<BATCH, 256, 0, stream>>>(xg, Whh, bhh, hst, Tc);
  }
  fc_kernel<<<BATCH, 128, 0, stream>>>(hst, fcw, fcb, out);
}

// Round 4
// 1350.876 us; speedup vs baseline: 5.2445x; 1.6415x over previous
//
#include <hip/hip_runtime.h>
#include <hip/hip_bf16.h>
#include <cstdint>
#include <cstddef>

typedef __attribute__((ext_vector_type(4))) float floatx4;
typedef __attribute__((ext_vector_type(8))) short shortx8;
typedef __attribute__((ext_vector_type(2))) __fp16 f16x2;

#define T_SEQ 512
#define NIN   512
#define BATCH 256
#define HID   256
#define G3    768
#define NC    101

static __device__ __forceinline__ unsigned short f2bf(float f){
  unsigned int u = __float_as_uint(f);
  u += 0x7FFFu + ((u >> 16) & 1u);
  return (unsigned short)(u >> 16);
}

static __device__ __forceinline__ float dot2acc(f16x2 w, f16x2 h, float acc){
#if __has_builtin(__builtin_amdgcn_fdot2)
  return __builtin_amdgcn_fdot2(w, h, acc, false);
#else
  return acc + (float)w[0]*(float)h[0] + (float)w[1]*(float)h[1];
#endif
}

// ---------------- Phase A: xg[b*Tc+tt][n] = x[b, t0+tt, :] . Wih[n, :] + bih[n]
#define BM 128
#define BN 128
#define BK 64
#define LDK 72

__global__ __launch_bounds__(256) void gemm_xg(
    const float* __restrict__ x, const float* __restrict__ Wih,
    const float* __restrict__ bih, float* __restrict__ xg,
    int t0, int tcLog2)
{
  __shared__ unsigned short As[BM*LDK];
  __shared__ unsigned short Bs[BN*LDK];
  const int tid  = threadIdx.x;
  const int bm   = blockIdx.x;
  const int bn   = blockIdx.y;
  const int w    = tid >> 6;
  const int l    = tid & 63;
  const int lm   = l & 15;
  const int quad = l >> 4;

  const int srow = tid >> 4;
  const int scol = (tid & 15) * 4;
  const int tcMask = (1 << tcLog2) - 1;

  floatx4 acc[2][8];
  #pragma unroll
  for (int mt = 0; mt < 2; ++mt)
    #pragma unroll
    for (int nt = 0; nt < 8; ++nt)
      acc[mt][nt] = (floatx4){0.f, 0.f, 0.f, 0.f};

  for (int kt = 0; kt < NIN / BK; ++kt){
    const int k0 = kt * BK;
    __syncthreads();
    #pragma unroll
    for (int p = 0; p < 8; ++p){
      const int r  = p * 16 + srow;
      const int gm = bm * BM + r;
      const int b  = gm >> tcLog2;
      const int tt = gm & tcMask;
      const float4 xa = *(const float4*)(x + (size_t)(b * T_SEQ + t0 + tt) * NIN + k0 + scol);
      union { unsigned short u[4]; uint2 v; } pa;
      pa.u[0] = f2bf(xa.x); pa.u[1] = f2bf(xa.y); pa.u[2] = f2bf(xa.z); pa.u[3] = f2bf(xa.w);
      *(uint2*)&As[r * LDK + scol] = pa.v;
      const int gn = bn * BN + r;
      const float4 wb = *(const float4*)(Wih + (size_t)gn * NIN + k0 + scol);
      union { unsigned short u[4]; uint2 v; } pb;
      pb.u[0] = f2bf(wb.x); pb.u[1] = f2bf(wb.y); pb.u[2] = f2bf(wb.z); pb.u[3] = f2bf(wb.w);
      *(uint2*)&Bs[r * LDK + scol] = pb.v;
    }
    __syncthreads();
    #pragma unroll
    for (int ks = 0; ks < 2; ++ks){
      const int kk = ks * 32 + quad * 8;
      shortx8 af[2], bfr[8];
      #pragma unroll
      for (int mt = 0; mt < 2; ++mt)
        af[mt] = *(const shortx8*)&As[(w * 32 + mt * 16 + lm) * LDK + kk];
      #pragma unroll
      for (int nt = 0; nt < 8; ++nt)
        bfr[nt] = *(const shortx8*)&Bs[(nt * 16 + lm) * LDK + kk];
      #pragma unroll
      for (int mt = 0; mt < 2; ++mt)
        #pragma unroll
        for (int nt = 0; nt < 8; ++nt)
          acc[mt][nt] = __builtin_amdgcn_mfma_f32_16x16x32_bf16(af[mt], bfr[nt], acc[mt][nt], 0, 0, 0);
    }
  }

  #pragma unroll
  for (int mt = 0; mt < 2; ++mt){
    #pragma unroll
    for (int nt = 0; nt < 8; ++nt){
      #pragma unroll
      for (int i = 0; i < 4; ++i){
        const int ml = w * 32 + mt * 16 + quad * 4 + i;
        const int nl = nt * 16 + lm;
        const int gm = bm * BM + ml;
        const int gn = bn * BN + nl;
        xg[(size_t)gm * G3 + gn] = acc[mt][nt][i] + bih[gn];
      }
    }
  }
}

// ---------------- Phase B: sequential GRU, split-K lane pairs.
// WG = 512 threads per batch element. tid = 2*j + half: thread owns the
// k-range [half*128, half*128+128) of Whh rows {j, j+256, j+512} as f16
// pairs (96 VGPRs). Partner lane (tid^1, same wave) holds the other half;
// partials combine with __shfl_xor — no extra barrier. 8 waves = 2/SIMD.
__global__ __launch_bounds__(512, 2) void gru_steps(
    const float* __restrict__ xg, const float* __restrict__ Whh,
    const float* __restrict__ bhh, float* __restrict__ hstate, int Tc)
{
  __shared__ alignas(16) unsigned short hph[HID];  // packed f16 h
  const int b    = blockIdx.x;
  const int tid  = threadIdx.x;
  const int j    = tid >> 1;
  const int half = tid & 1;

  // 3 gates x 64 f16-pairs = 96 VGPRs of weights.
  f16x2 wrr[64], wrz[64], wrn[64];
  {
    const float4* r4 = (const float4*)(Whh + (size_t)j * HID + half * 128);
    const float4* z4 = (const float4*)(Whh + (size_t)(j + 256) * HID + half * 128);
    const float4* n4 = (const float4*)(Whh + (size_t)(j + 512) * HID + half * 128);
    #pragma unroll
    for (int k = 0; k < 32; ++k){
      float4 v = r4[k];
      wrr[2*k]   = __builtin_amdgcn_cvt_pkrtz(v.x, v.y);
      wrr[2*k+1] = __builtin_amdgcn_cvt_pkrtz(v.z, v.w);
    }
    #pragma unroll
    for (int k = 0; k < 32; ++k){
      float4 v = z4[k];
      wrz[2*k]   = __builtin_amdgcn_cvt_pkrtz(v.x, v.y);
      wrz[2*k+1] = __builtin_amdgcn_cvt_pkrtz(v.z, v.w);
    }
    #pragma unroll
    for (int k = 0; k < 32; ++k){
      float4 v = n4[k];
      wrn[2*k]   = __builtin_amdgcn_cvt_pkrtz(v.x, v.y);
      wrn[2*k+1] = __builtin_amdgcn_cvt_pkrtz(v.z, v.w);
    }
  }
  const float br = bhh[j];
  const float bz = bhh[j + 256];
  const float bn = bhh[j + 512];

  float hj = hstate[b * HID + j];
  if (half == 0){
    union { __fp16 f; unsigned short u; } cv;
    cv.f = (__fp16)hj;
    hph[j] = cv.u;
  }
  __syncthreads();

  const float* xgrow = xg + (size_t)b * Tc * G3 + j;

  // Prefetch step 0.
  float xr = xgrow[0], xz = xgrow[256], xn = xgrow[512];

  #pragma unroll 1
  for (int t = 0; t < Tc; ++t){
    // Prefetch t+1 (consumed next iteration; hides HBM latency behind dots).
    const int tn = (t + 1 < Tc) ? (t + 1) : t;
    const float nxr = xgrow[(size_t)tn * G3];
    const float nxz = xgrow[(size_t)tn * G3 + 256];
    const float nxn = xgrow[(size_t)tn * G3 + 512];

    // Half-dots over this thread's 64 f16 pairs of h.
    float ar = 0.f, az = 0.f, an = 0.f;
    const uint4* hp4 = (const uint4*)hph + half * 16;  // 16 x uint4 = 64 pairs
    #pragma unroll
    for (int i = 0; i < 16; ++i){
      const uint4 hv = hp4[i];
      union { unsigned int u; f16x2 h; } c0, c1, c2, c3;
      c0.u = hv.x; c1.u = hv.y; c2.u = hv.z; c3.u = hv.w;
      const int p = 4 * i;
      ar = dot2acc(wrr[p    ], c0.h, ar);
      az = dot2acc(wrz[p    ], c0.h, az);
      an = dot2acc(wrn[p    ], c0.h, an);
      ar = dot2acc(wrr[p + 1], c1.h, ar);
      az = dot2acc(wrz[p + 1], c1.h, az);
      an = dot2acc(wrn[p + 1], c1.h, an);
      ar = dot2acc(wrr[p + 2], c2.h, ar);
      az = dot2acc(wrz[p + 2], c2.h, az);
      an = dot2acc(wrn[p + 2], c2.h, an);
      ar = dot2acc(wrr[p + 3], c3.h, ar);
      az = dot2acc(wrz[p + 3], c3.h, az);
      an = dot2acc(wrn[p + 3], c3.h, an);
    }
    // Combine with partner lane (tid^1): both lanes get full sums.
    const float hr = ar + __shfl_xor(ar, 1, 64) + br;
    const float hz = az + __shfl_xor(az, 1, 64) + bz;
    const float hn = an + __shfl_xor(an, 1, 64) + bn;

    const float r = 1.f / (1.f + __expf(-(xr + hr)));
    const float z = 1.f / (1.f + __expf(-(xz + hz)));
    const float a = xn + r * hn;
    const float ex = __expf(-2.f * fabsf(a));
    float n = (1.f - ex) / (1.f + ex);
    n = copysignf(n, a);
    const float hnew = fmaf(z, hj - n, n);   // (1-z)*n + z*h

    __syncthreads();   // all reads of old h done
    hj = hnew;
    if (half == 0){
      union { __fp16 f; unsigned short u; } cv;
      cv.f = (__fp16)hj;
      hph[j] = cv.u;
    }
    __syncthreads();   // new h visible
    xr = nxr; xz = nxz; xn = nxn;
  }

  if (half == 0) hstate[b * HID + j] = hj;
}

// ---------------- FC: out[b][c] = h[b,:] . fc_w[c,:] + fc_b[c]
__global__ __launch_bounds__(128) void fc_kernel(
    const float* __restrict__ hstate, const float* __restrict__ fw,
    const float* __restrict__ fb, float* __restrict__ out)
{
  __shared__ float hs[HID];
  const int b = blockIdx.x;
  const int t = threadIdx.x;
  hs[t]       = hstate[b * HID + t];
  hs[t + 128] = hstate[b * HID + t + 128];
  __syncthreads();
  if (t < NC){
    float acc = fb[t];
    const float4* w4 = (const float4*)(fw + (size_t)t * HID);
    const float4* h4 = (const float4*)hs;
    #pragma unroll
    for (int k = 0; k < 64; ++k){
      const float4 wv = w4[k];
      const float4 hv = h4[k];
      acc += wv.x * hv.x + wv.y * hv.y + wv.z * hv.z + wv.w * hv.w;
    }
    out[b * NC + t] = acc;
  }
}

extern "C" void kernel_launch(void* const* d_in, const int* in_sizes, int n_in,
                              void* d_out, int out_size, void* d_ws, size_t ws_size,
                              hipStream_t stream)
{
  const float* x   = (const float*)d_in[0];
  const float* Wih = (const float*)d_in[1];
  const float* Whh = (const float*)d_in[2];
  const float* bih = (const float*)d_in[3];
  const float* bhh = (const float*)d_in[4];
  const float* fcw = (const float*)d_in[5];
  const float* fcb = (const float*)d_in[6];
  float* out = (float*)d_out;

  float* hst = (float*)d_ws;
  const size_t hBytes = (size_t)BATCH * HID * sizeof(float);
  float* xg  = (float*)((char*)d_ws + hBytes);

  const size_t perT = (size_t)BATCH * G3 * sizeof(float);
  const size_t avail = (ws_size > hBytes) ? (ws_size - hBytes) : 0;
  int tcLog2 = 9;
  while (tcLog2 > 0 && perT * ((size_t)1 << tcLog2) > avail) --tcLog2;
  const int Tc = 1 << tcLog2;

  (void)hipMemsetAsync(hst, 0, hBytes, stream);
  for (int t0 = 0; t0 < T_SEQ; t0 += Tc){
    dim3 grid(2 * Tc, 6);
    gemm_xg<<<grid, 256, 0, stream>>>(x, Wih, bih, xg, t0, tcLog2);
    gru_steps<<<BATCH, 512, 0, stream>>>(xg, Whh, bhh, hst, Tc);
  }
  fc_kernel<<<BATCH, 128, 0, stream>>>(hst, fcw, fcb, out);
}

// Round 5
// 1283.183 us; speedup vs baseline: 5.5212x; 1.0528x over previous
//
#include <hip/hip_runtime.h>
#include <hip/hip_bf16.h>
#include <cstdint>
#include <cstddef>

typedef __attribute__((ext_vector_type(4))) float floatx4;
typedef __attribute__((ext_vector_type(8))) short shortx8;
typedef __attribute__((ext_vector_type(2))) __fp16 f16x2;

#define T_SEQ 512
#define NIN   512
#define BATCH 256
#define HID   256
#define G3    768
#define NC    101

static __device__ __forceinline__ unsigned short f2bf(float f){
  unsigned int u = __float_as_uint(f);
  u += 0x7FFFu + ((u >> 16) & 1u);
  return (unsigned short)(u >> 16);
}

static __device__ __forceinline__ float dot2acc(f16x2 w, f16x2 h, float acc){
#if __has_builtin(__builtin_amdgcn_fdot2)
  return __builtin_amdgcn_fdot2(w, h, acc, false);
#else
  return acc + (float)w[0]*(float)h[0] + (float)w[1]*(float)h[1];
#endif
}

// ---------------- Phase A: xg[b*Tc+tt][n] = x[b, t0+tt, :] . Wih[n, :] + bih[n]
#define BM 128
#define BN 128
#define BK 64
#define LDK 72

__global__ __launch_bounds__(256) void gemm_xg(
    const float* __restrict__ x, const float* __restrict__ Wih,
    const float* __restrict__ bih, float* __restrict__ xg,
    int t0, int tcLog2)
{
  __shared__ unsigned short As[BM*LDK];
  __shared__ unsigned short Bs[BN*LDK];
  const int tid  = threadIdx.x;
  const int bn   = blockIdx.x;   // N fastest: 6 consecutive blocks share one x-tile (L2 reuse)
  const int bm   = blockIdx.y;
  const int w    = tid >> 6;
  const int l    = tid & 63;
  const int lm   = l & 15;
  const int quad = l >> 4;

  const int srow = tid >> 4;
  const int scol = (tid & 15) * 4;
  const int tcMask = (1 << tcLog2) - 1;

  floatx4 acc[2][8];
  #pragma unroll
  for (int mt = 0; mt < 2; ++mt)
    #pragma unroll
    for (int nt = 0; nt < 8; ++nt)
      acc[mt][nt] = (floatx4){0.f, 0.f, 0.f, 0.f};

  for (int kt = 0; kt < NIN / BK; ++kt){
    const int k0 = kt * BK;
    __syncthreads();
    #pragma unroll
    for (int p = 0; p < 8; ++p){
      const int r  = p * 16 + srow;
      const int gm = bm * BM + r;
      const int b  = gm >> tcLog2;
      const int tt = gm & tcMask;
      const float4 xa = *(const float4*)(x + (size_t)(b * T_SEQ + t0 + tt) * NIN + k0 + scol);
      union { unsigned short u[4]; uint2 v; } pa;
      pa.u[0] = f2bf(xa.x); pa.u[1] = f2bf(xa.y); pa.u[2] = f2bf(xa.z); pa.u[3] = f2bf(xa.w);
      *(uint2*)&As[r * LDK + scol] = pa.v;
      const int gn = bn * BN + r;
      const float4 wb = *(const float4*)(Wih + (size_t)gn * NIN + k0 + scol);
      union { unsigned short u[4]; uint2 v; } pb;
      pb.u[0] = f2bf(wb.x); pb.u[1] = f2bf(wb.y); pb.u[2] = f2bf(wb.z); pb.u[3] = f2bf(wb.w);
      *(uint2*)&Bs[r * LDK + scol] = pb.v;
    }
    __syncthreads();
    #pragma unroll
    for (int ks = 0; ks < 2; ++ks){
      const int kk = ks * 32 + quad * 8;
      shortx8 af[2], bfr[8];
      #pragma unroll
      for (int mt = 0; mt < 2; ++mt)
        af[mt] = *(const shortx8*)&As[(w * 32 + mt * 16 + lm) * LDK + kk];
      #pragma unroll
      for (int nt = 0; nt < 8; ++nt)
        bfr[nt] = *(const shortx8*)&Bs[(nt * 16 + lm) * LDK + kk];
      #pragma unroll
      for (int mt = 0; mt < 2; ++mt)
        #pragma unroll
        for (int nt = 0; nt < 8; ++nt)
          acc[mt][nt] = __builtin_amdgcn_mfma_f32_16x16x32_bf16(af[mt], bfr[nt], acc[mt][nt], 0, 0, 0);
    }
  }

  #pragma unroll
  for (int mt = 0; mt < 2; ++mt){
    #pragma unroll
    for (int nt = 0; nt < 8; ++nt){
      #pragma unroll
      for (int i = 0; i < 4; ++i){
        const int ml = w * 32 + mt * 16 + quad * 4 + i;
        const int nl = nt * 16 + lm;
        const int gm = bm * BM + ml;
        const int gn = bn * BN + nl;
        xg[(size_t)gm * G3 + gn] = acc[mt][nt][i] + bih[gn];
      }
    }
  }
}

// ---------------- Phase B: sequential GRU, split-K lane pairs.
// tid = 2*j + half. 96 VGPRs of f16 weights per thread. h mirror in LDS is
// DOUBLE-BUFFERED (1 barrier/step) and the half1 region is padded +16 B so
// the wave's two read addresses hit disjoint 4-bank groups (no conflicts).
// Full h half preloaded into 16 uint4 regs before the dot loop.
#define HSTRIDE 280   // uint16 elems per buffer (256 + 8 pad + pad-to-16B)

__global__ __launch_bounds__(512, 2) void gru_steps(
    const float* __restrict__ xg, const float* __restrict__ Whh,
    const float* __restrict__ bhh, float* __restrict__ hstate, int Tc)
{
  __shared__ alignas(16) unsigned short hph[2][HSTRIDE];
  const int b    = blockIdx.x;
  const int tid  = threadIdx.x;
  const int j    = tid >> 1;
  const int half = tid & 1;
  const int jpos = j + (j >= 128 ? 8 : 0);   // +16B pad between halves

  f16x2 wrr[64], wrz[64], wrn[64];
  {
    const float4* r4 = (const float4*)(Whh + (size_t)j * HID + half * 128);
    const float4* z4 = (const float4*)(Whh + (size_t)(j + 256) * HID + half * 128);
    const float4* n4 = (const float4*)(Whh + (size_t)(j + 512) * HID + half * 128);
    #pragma unroll
    for (int k = 0; k < 32; ++k){
      float4 v = r4[k];
      wrr[2*k]   = __builtin_amdgcn_cvt_pkrtz(v.x, v.y);
      wrr[2*k+1] = __builtin_amdgcn_cvt_pkrtz(v.z, v.w);
    }
    #pragma unroll
    for (int k = 0; k < 32; ++k){
      float4 v = z4[k];
      wrz[2*k]   = __builtin_amdgcn_cvt_pkrtz(v.x, v.y);
      wrz[2*k+1] = __builtin_amdgcn_cvt_pkrtz(v.z, v.w);
    }
    #pragma unroll
    for (int k = 0; k < 32; ++k){
      float4 v = n4[k];
      wrn[2*k]   = __builtin_amdgcn_cvt_pkrtz(v.x, v.y);
      wrn[2*k+1] = __builtin_amdgcn_cvt_pkrtz(v.z, v.w);
    }
  }
  const float br = bhh[j];
  const float bz = bhh[j + 256];
  const float bn = bhh[j + 512];

  float hj = hstate[b * HID + j];
  if (half == 0){
    union { __fp16 f; unsigned short u; } cv;
    cv.f = (__fp16)hj;
    hph[0][jpos] = cv.u;
  }
  __syncthreads();

  const float* xgrow = xg + (size_t)b * Tc * G3 + j;
  float xr = xgrow[0], xz = xgrow[256], xn = xgrow[512];

  #pragma unroll 1
  for (int t = 0; t < Tc; ++t){
    const int tn = (t + 1 < Tc) ? (t + 1) : t;
    const float nxr = xgrow[(size_t)tn * G3];
    const float nxz = xgrow[(size_t)tn * G3 + 256];
    const float nxn = xgrow[(size_t)tn * G3 + 512];

    // Preload this thread's 64 h-pairs (272-B aligned region; 17 uint4 stride).
    const uint4* hp4 = (const uint4*)(&hph[t & 1][0]) + half * 17;
    uint4 hv[16];
    #pragma unroll
    for (int i = 0; i < 16; ++i) hv[i] = hp4[i];

    float ar = 0.f, az = 0.f, an = 0.f;
    #pragma unroll
    for (int i = 0; i < 16; ++i){
      union { unsigned int u; f16x2 h; } c0, c1, c2, c3;
      c0.u = hv[i].x; c1.u = hv[i].y; c2.u = hv[i].z; c3.u = hv[i].w;
      const int p = 4 * i;
      ar = dot2acc(wrr[p    ], c0.h, ar);
      az = dot2acc(wrz[p    ], c0.h, az);
      an = dot2acc(wrn[p    ], c0.h, an);
      ar = dot2acc(wrr[p + 1], c1.h, ar);
      az = dot2acc(wrz[p + 1], c1.h, az);
      an = dot2acc(wrn[p + 1], c1.h, an);
      ar = dot2acc(wrr[p + 2], c2.h, ar);
      az = dot2acc(wrz[p + 2], c2.h, az);
      an = dot2acc(wrn[p + 2], c2.h, an);
      ar = dot2acc(wrr[p + 3], c3.h, ar);
      az = dot2acc(wrz[p + 3], c3.h, az);
      an = dot2acc(wrn[p + 3], c3.h, an);
    }
    const float hr = ar + __shfl_xor(ar, 1, 64) + br;
    const float hz = az + __shfl_xor(az, 1, 64) + bz;
    const float hn = an + __shfl_xor(an, 1, 64) + bn;

    const float r = 1.f / (1.f + __expf(-(xr + hr)));
    const float z = 1.f / (1.f + __expf(-(xz + hz)));
    const float a = xn + r * hn;
    const float ex = __expf(-2.f * fabsf(a));
    float n = (1.f - ex) / (1.f + ex);
    n = copysignf(n, a);
    const float hnew = fmaf(z, hj - n, n);   // (1-z)*n + z*h

    hj = hnew;
    if (half == 0){
      union { __fp16 f; unsigned short u; } cv;
      cv.f = (__fp16)hj;
      hph[1 - (t & 1)][jpos] = cv.u;   // write other buffer: no race with reads
    }
    __syncthreads();                    // single barrier: new buffer visible
    xr = nxr; xz = nxz; xn = nxn;
  }

  if (half == 0) hstate[b * HID + j] = hj;
}

// ---------------- FC
__global__ __launch_bounds__(128) void fc_kernel(
    const float* __restrict__ hstate, const float* __restrict__ fw,
    const float* __restrict__ fb, float* __restrict__ out)
{
  __shared__ float hs[HID];
  const int b = blockIdx.x;
  const int t = threadIdx.x;
  hs[t]       = hstate[b * HID + t];
  hs[t + 128] = hstate[b * HID + t + 128];
  __syncthreads();
  if (t < NC){
    float acc = fb[t];
    const float4* w4 = (const float4*)(fw + (size_t)t * HID);
    const float4* h4 = (const float4*)hs;
    #pragma unroll
    for (int k = 0; k < 64; ++k){
      const float4 wv = w4[k];
      const float4 hv = h4[k];
      acc += wv.x * hv.x + wv.y * hv.y + wv.z * hv.z + wv.w * hv.w;
    }
    out[b * NC + t] = acc;
  }
}

extern "C" void kernel_launch(void* const* d_in, const int* in_sizes, int n_in,
                              void* d_out, int out_size, void* d_ws, size_t ws_size,
                              hipStream_t stream)
{
  const float* x   = (const float*)d_in[0];
  const float* Wih = (const float*)d_in[1];
  const float* Whh = (const float*)d_in[2];
  const float* bih = (const float*)d_in[3];
  const float* bhh = (const float*)d_in[4];
  const float* fcw = (const float*)d_in[5];
  const float* fcb = (const float*)d_in[6];
  float* out = (float*)d_out;

  float* hst = (float*)d_ws;
  const size_t hBytes = (size_t)BATCH * HID * sizeof(float);
  float* xg  = (float*)((char*)d_ws + hBytes);

  const size_t perT = (size_t)BATCH * G3 * sizeof(float);
  const size_t avail = (ws_size > hBytes) ? (ws_size - hBytes) : 0;
  int tcLog2 = 9;
  while (tcLog2 > 0 && perT * ((size_t)1 << tcLog2) > avail) --tcLog2;
  const int Tc = 1 << tcLog2;

  (void)hipMemsetAsync(hst, 0, hBytes, stream);
  for (int t0 = 0; t0 < T_SEQ; t0 += Tc){
    dim3 grid(6, 2 * Tc);
    gemm_xg<<<grid, 256, 0, stream>>>(x, Wih, bih, xg, t0, tcLog2);
    gru_steps<<<BATCH, 512, 0, stream>>>(xg, Whh, bhh, hst, Tc);
  }
  fc_kernel<<<BATCH, 128, 0, stream>>>(hst, fcw, fcb, out);
}